// Round 16
// baseline (204.052 us; speedup 1.0000x reference)
//
#include <hip/hip_runtime.h>
#include <stdint.h>

// S6Layer on MI355X. B=8, L=4096, DM=256, DI=384, DS=8, CHUNK=32.
// R22 = R21 resubmitted verbatim (container acquisition failed, zero signal).
// R21, from R14 counters (s6_head 73.2us, MfmaUtil 10.2% = dense-packed MFMA
// floor already, VALUBusy 60.7% -> VALU-ISSUE-BOUND):
//  sOut TRANSPOSED to [ch][token] with the proven 16B-chunk XOR swizzle
//  (j=tok>>3, jp=(j&~7)|((j&7)^(ch&7))):
//   - scan: 96 scalar ds_read_u16 + per-iter idx math  ->  12 ds_read_b128
//     (8 tokens per load), zero per-iter address VALU.
//   - EPI: 96 scalar ds_write_b16 -> 24 ds_write_b64 (pack 4 tokens as
//     2 u32 via f2bf|f2bf<<16; rm0&7 in {0,4} -> 8B aligned).
//  Same f2bf rounding points -> bit-identical output.
// R20 kept: A-frag preload (shared by 3 subs), exp2f scan, prep1/prep2 split,
// gemm_out coalesced fp32 epilogue, R16 W_eff algebra, R12 swizzles.
// Pipeline: cvt, prep1, prep2, ln, s6_head, gemm_out.
#define B_  8
#define L_  4096
#define DM  256
#define DI  384
#define DS  8
#define M_  (B_*L_)   // 32768 tokens

typedef float f32x4 __attribute__((ext_vector_type(4)));
typedef short s16x8 __attribute__((ext_vector_type(8)));

#define AS1(p) ((__attribute__((address_space(1))) void*)(p))
#define AS3(p) ((__attribute__((address_space(3))) void*)(p))

__device__ __forceinline__ unsigned short f2bf(float f) {
  union { float f; uint32_t u; } v; v.f = f;
  uint32_t r = v.u + 0x7FFFu + ((v.u >> 16) & 1u);   // RNE
  return (unsigned short)(r >> 16);
}
__device__ __forceinline__ float bf2f(unsigned short h) {
  union { uint32_t u; float f; } v; v.u = ((uint32_t)h) << 16;
  return v.f;
}
__device__ __forceinline__ float silu_f(float x) {
  return x * __builtin_amdgcn_rcpf(1.f + __expf(-x));
}

// ---------------- weight fp32 -> bf16 (+ b_in copy into combined bias) -----
__global__ __launch_bounds__(256) void cvt_kernel(
    const float* __restrict__ w0, const float* __restrict__ w2,
    const float* __restrict__ b_in,
    unsigned short* __restrict__ o0, unsigned short* __restrict__ o2,
    float* __restrict__ biasc) {
  int i = blockIdx.x * 256 + threadIdx.x;
  if (i < 3*DI*DM) o0[i] = f2bf(w0[i]);
  if (i < DM*DI)   o2[i] = f2bf(w2[i]);
  if (i < 2*DI)    biasc[i] = b_in[i];
}

// ---------------- prep1: W_eff partials over k-chunks of 96 ----------------
__global__ __launch_bounds__(256) void prep1_kernel(
    const float* __restrict__ W_in, const float* __restrict__ b_in,
    const float* __restrict__ W_dt,
    float* __restrict__ scr, float* __restrict__ bscr) {
  const int n  = blockIdx.x;
  const int kc = blockIdx.y;
  const int c  = threadIdx.x;
  const int kb = kc * 96;
  const float* wd = W_dt + (size_t)n*DI + kb;
  const float* wi = W_in + (size_t)(2*DI + kb)*DM + c;
  float p0 = 0.f, p1 = 0.f, p2 = 0.f, p3 = 0.f;
  #pragma unroll
  for (int k = 0; k < 96; k += 4) {
    p0 += wd[k+0] * wi[(size_t)(k+0)*DM];
    p1 += wd[k+1] * wi[(size_t)(k+1)*DM];
    p2 += wd[k+2] * wi[(size_t)(k+2)*DM];
    p3 += wd[k+3] * wi[(size_t)(k+3)*DM];
  }
  scr[(size_t)(n*4 + kc)*256 + c] = (p0 + p1) + (p2 + p3);
  if (c < 64) {
    float p = wd[c] * b_in[2*DI + kb + c];
    if (c < 32) p += wd[64 + c] * b_in[2*DI + kb + 64 + c];
    #pragma unroll
    for (int off = 32; off > 0; off >>= 1) p += __shfl_down(p, off, 64);
    if (c == 0) bscr[n*4 + kc] = p;
  }
}

// ---------------- prep2: sum 4 partials -> winb dt-slice; b_eff -> biasc ---
__global__ __launch_bounds__(256) void prep2_kernel(
    const float* __restrict__ scr, const float* __restrict__ bscr,
    const float* __restrict__ b_dt,
    unsigned short* __restrict__ winb, float* __restrict__ biasc) {
  const int n = blockIdx.x, c = threadIdx.x;
  const float* s = scr + (size_t)n*4*256 + c;
  winb[(size_t)(2*DI + n)*DM + c] = f2bf((s[0] + s[256]) + (s[512] + s[768]));
  if (c == 0)
    biasc[2*DI + n] = b_dt[n] + ((bscr[n*4] + bscr[n*4+1]) + (bscr[n*4+2] + bscr[n*4+3]));
}

// ---------------- layernorm: one wave per token ----------------
__global__ __launch_bounds__(256) void ln_kernel(
    const float* __restrict__ x, const float* __restrict__ gamma, const float* __restrict__ beta,
    unsigned short* __restrict__ xn) {
  int token = blockIdx.x * 4 + (threadIdx.x >> 6);
  int lane  = threadIdx.x & 63;
  const float4 v = *(const float4*)(x + (size_t)token*DM + lane*4);
  float s  = v.x + v.y + v.z + v.w;
  float ss = v.x*v.x + v.y*v.y + v.z*v.z + v.w*v.w;
  #pragma unroll
  for (int off = 32; off > 0; off >>= 1) {
    s  += __shfl_xor(s,  off, 64);
    ss += __shfl_xor(ss, off, 64);
  }
  float mean = s * (1.f/DM);
  float var  = ss * (1.f/DM) - mean*mean;
  float rstd = rsqrtf(var + 1e-5f);
  const float4 g = *(const float4*)(gamma + lane*4);
  const float4 b = *(const float4*)(beta  + lane*4);
  ushort4 o;
  o.x = f2bf((v.x - mean)*rstd*g.x + b.x);
  o.y = f2bf((v.y - mean)*rstd*g.y + b.y);
  o.z = f2bf((v.z - mean)*rstd*g.z + b.z);
  o.w = f2bf((v.w - mean)*rstd*g.w + b.w);
  *(ushort4*)(xn + (size_t)token*DM + lane*4) = o;
}

// ---------------- fused head: xp/z/dt sub-GEMMs + chunked scan -> yz -------
// Block = 128 tokens x 64 channels; grid 1536. sOutT[sub][ch][tok] with
// 16B-chunk XOR swizzle (jp = (j&~7)|((j&7)^(ch&7)), j = tok>>3).
__global__ __launch_bounds__(256, 2) void s6_head(
    const unsigned short* __restrict__ xn,   // [M,256] bf16
    const unsigned short* __restrict__ Wb,   // [1152,256] bf16 (xp|z|W_eff)
    const float* __restrict__ biasc,         // [1152]
    const float* __restrict__ A_log, const float* __restrict__ D_vec,
    unsigned short* __restrict__ yz)         // [M,384] bf16
{
  constexpr int K = 256, CPR = K/8;
  __shared__ unsigned short sB[64*K];          // 32KB
  __shared__ unsigned short sOutT[3][64*128];  // 48KB, [ch][tok] swizzled
  const int t    = threadIdx.x;
  const int lane = t & 63;
  const int w    = t >> 6;
  const int fr   = lane & 15;
  const int fq   = lane >> 4;
  const int wm   = w * 32;

  const int q      = blockIdx.x;
  const int u      = q >> 3;
  const int mtile  = (q & 7) * 32 + (u & 31);   // 0..255
  const int panel  = u >> 5;                    // 0..5
  const int mbase  = mtile * 128;
  const int chbase = panel * 64;

  const unsigned short* gA0 = xn + (size_t)(mbase + wm + fr)*K + fq*8;
  const unsigned short* gA1 = gA0 + (size_t)16*K;
  const unsigned short* sBrE = sB + (size_t)fr*K + ( fq      ^ (fr & 7))*8;
  const unsigned short* sBrO = sB + (size_t)fr*K + ((fq | 4) ^ (fr & 7))*8;

  // ---- preload ALL A-frags once (shared by the 3 sub-GEMMs) ----
  s16x8 afr[8][2];
  #pragma unroll
  for (int kt = 0; kt < 8; ++kt) {
    afr[kt][0] = *(const s16x8*)(gA0 + kt*32);
    afr[kt][1] = *(const s16x8*)(gA1 + kt*32);
  }

  auto STAGE = [&](int sub) {
    const int nb = sub*DI + chbase;
    #pragma unroll
    for (int i = 0; i < (64*CPR)/256; ++i) {
      int c   = i*256 + t;
      int row = c / CPR;
      int j   = c - row*CPR;
      int jp  = (j & ~7) | ((j & 7) ^ (row & 7));
      __builtin_amdgcn_global_load_lds(AS1(Wb + (size_t)(nb + row)*K + jp*8),
                                       AS3(sB + c*8), 16, 0, 0);
    }
  };
  auto KLOOP = [&](f32x4 (&acc)[2][4]) {
    #pragma unroll
    for (int mi = 0; mi < 2; ++mi)
      #pragma unroll
      for (int ni = 0; ni < 4; ++ni) acc[mi][ni] = (f32x4){0.f, 0.f, 0.f, 0.f};
    #pragma unroll
    for (int kt = 0; kt < 8; ++kt) {
      const unsigned short* bb = (kt & 1) ? sBrO : sBrE;
      s16x8 bfr[4];
      #pragma unroll
      for (int ni = 0; ni < 4; ++ni)
        bfr[ni] = *(const s16x8*)(bb + ni*16*K + (kt >> 1)*64);
      #pragma unroll
      for (int ni = 0; ni < 4; ++ni) {
        acc[0][ni] = __builtin_amdgcn_mfma_f32_16x16x32_bf16(afr[kt][0], bfr[ni], acc[0][ni], 0, 0, 0);
        acc[1][ni] = __builtin_amdgcn_mfma_f32_16x16x32_bf16(afr[kt][1], bfr[ni], acc[1][ni], 0, 0, 0);
      }
    }
  };
  // EPI: thread owns ch=cn, tokens rm0..rm0+3 (rm0 = wm+mi*16+fq*4, &7 in
  // {0,4}). Pack 4 tokens -> 2 u32 -> one ds_write_b64 at the swizzled slot.
  auto EPI = [&](f32x4 (&acc)[2][4], int sub) {
    const int nb = sub*DI + chbase;
    const bool sl = (sub < 2);
    unsigned short* so = &sOutT[sub][0];
    #pragma unroll
    for (int ni = 0; ni < 4; ++ni) {
      float bv = biasc[nb + ni*16 + fr];
      int cn = ni*16 + fr;
      #pragma unroll
      for (int mi = 0; mi < 2; ++mi) {
        int rm0 = wm + mi*16 + fq*4;
        int j   = rm0 >> 3;
        int jp  = (j & ~7) | ((j & 7) ^ (cn & 7));
        float c0 = acc[mi][ni][0] + bv, c1 = acc[mi][ni][1] + bv;
        float c2 = acc[mi][ni][2] + bv, c3 = acc[mi][ni][3] + bv;
        if (sl) { c0 = silu_f(c0); c1 = silu_f(c1); c2 = silu_f(c2); c3 = silu_f(c3); }
        else {
          c0 = (c0 > 20.f) ? c0 : __logf(1.f + __expf(c0));
          c1 = (c1 > 20.f) ? c1 : __logf(1.f + __expf(c1));
          c2 = (c2 > 20.f) ? c2 : __logf(1.f + __expf(c2));
          c3 = (c3 > 20.f) ? c3 : __logf(1.f + __expf(c3));
        }
        uint2 pk;
        pk.x = (uint32_t)f2bf(c0) | ((uint32_t)f2bf(c1) << 16);
        pk.y = (uint32_t)f2bf(c2) | ((uint32_t)f2bf(c3) << 16);
        *(uint2*)(so + cn*128 + jp*8 + (rm0 & 7)) = pk;
      }
    }
  };

  f32x4 aP[2][4], aC[2][4];
  STAGE(0);
  __syncthreads();                 // sB(0) + afr resident
  KLOOP(aP);
  __syncthreads();                 // all waves done reading sB(0)
  STAGE(1);                        // DMA under the epilogue VALU
  EPI(aP, 0);
  __syncthreads();                 // drains vmcnt -> sB(1) resident
  KLOOP(aC);
  __syncthreads();
  STAGE(2);
  EPI(aC, 1);
  __syncthreads();
  KLOOP(aP);
  EPI(aP, 2);
  __syncthreads();                 // sOutT[0..2] visible to all waves

  // ---- scan: (chunk c = wave, channel d = lane); 8 tokens per b128 ----
  {
    const int c  = t >> 6;        // chunk 0..3
    const int d  = t & 63;        // panel-local channel
    const int ch = chbase + d;    // global channel
    float a2[DS], h[DS];
    #pragma unroll
    for (int s = 0; s < DS; ++s) {
      a2[s] = -__expf(A_log[ch*DS + s]) * 1.44269504f;   // exp -> exp2
      h[s] = 0.f;
    }
    float Dv = D_vec[ch];
    unsigned short* yzp = yz + (size_t)(mbase + c*32)*DI + ch;
    const unsigned short* s0 = &sOutT[0][0] + d*128;
    const unsigned short* s1 = &sOutT[1][0] + d*128;
    const unsigned short* s2 = &sOutT[2][0] + d*128;
    #pragma unroll
    for (int jj = 0; jj < 4; ++jj) {
      int j   = c*4 + jj;
      int jp8 = ((j & ~7) | ((j & 7) ^ (d & 7))) * 8;   // u16 units
      s16x8 xv8 = *(const s16x8*)(s0 + jp8);
      s16x8 zv8 = *(const s16x8*)(s1 + jp8);
      s16x8 dv8 = *(const s16x8*)(s2 + jp8);
      #pragma unroll
      for (int uu = 0; uu < 8; ++uu) {
        float xv  = bf2f((unsigned short)xv8[uu]);
        float dtv = bf2f((unsigned short)dv8[uu]);
        float y = 0.f;
        #pragma unroll
        for (int s = 0; s < DS; ++s) {
          h[s] = h[s] * exp2f(dtv * a2[s]) + xv;
          y += h[s];
        }
        float zv = bf2f((unsigned short)zv8[uu]);
        yzp[(size_t)(jj*8 + uu)*DI] = f2bf(y * zv + xv * Dv);
      }
    }
  }
}

// ---------------- GEMM3: yz @ Wout^T + b_out + resid, coalesced epilogue ---
__global__ __launch_bounds__(256, 3) void gemm_out(
    const unsigned short* __restrict__ A,   // [M,384] bf16 (yz)
    const unsigned short* __restrict__ Bw,  // [256,384] bf16
    const float* __restrict__ bias,         // [256]
    const float* __restrict__ resid, float* __restrict__ o_f)
{
  constexpr int K = 384, CPR = K/8;
  __shared__ unsigned short sB[64*K];       // 48KB
  float* sC = (float*)sB;                   // overlay: [128][72] fp32 = 36.9KB

  const int t    = threadIdx.x;
  const int lane = t & 63;
  const int w    = t >> 6;
  const int fr   = lane & 15;
  const int fq   = lane >> 4;
  const int wm   = w * 32;

  const int q    = blockIdx.y * 256 + blockIdx.x;
  const int bx2  = (q & 7) * 32 + ((q >> 3) & 31);
  const int by2  = q >> 8;
  const int mbase = bx2 * 128;
  const int nbase = by2 * 64;

  #pragma unroll
  for (int i = 0; i < (64*CPR)/256; ++i) {
    int c   = i*256 + t;
    int row = c / CPR;
    int j   = c - row*CPR;
    int jp  = (j & ~7) | ((j & 7) ^ (row & 7));
    __builtin_amdgcn_global_load_lds(AS1(Bw + (size_t)(nbase + row)*K + jp*8),
                                     AS3(sB + c*8), 16, 0, 0);
  }

  const unsigned short* sBrE = sB + (size_t)fr*K + ( fq      ^ (fr & 7))*8;
  const unsigned short* sBrO = sB + (size_t)fr*K + ((fq | 4) ^ (fr & 7))*8;

  float bvv[4];
  #pragma unroll
  for (int ni = 0; ni < 4; ++ni) bvv[ni] = bias[nbase + ni*16 + fr];

  __syncthreads();   // B panel resident

  const unsigned short* gA0 = A + (size_t)(mbase + wm + fr)*K + fq*8;
  const unsigned short* gA1 = gA0 + (size_t)16*K;

  f32x4 acc[2][4];
  #pragma unroll
  for (int mi = 0; mi < 2; ++mi)
    #pragma unroll
    for (int ni = 0; ni < 4; ++ni) acc[mi][ni] = (f32x4){0.f, 0.f, 0.f, 0.f};

  #pragma unroll
  for (int kt = 0; kt < 12; ++kt) {
    s16x8 a0 = *(const s16x8*)(gA0 + kt*32);
    s16x8 a1 = *(const s16x8*)(gA1 + kt*32);
    const unsigned short* bb = (kt & 1) ? sBrO : sBrE;
    s16x8 bfr[4];
    #pragma unroll
    for (int ni = 0; ni < 4; ++ni)
      bfr[ni] = *(const s16x8*)(bb + ni*16*K + (kt >> 1)*64);
    #pragma unroll
    for (int ni = 0; ni < 4; ++ni) {
      acc[0][ni] = __builtin_amdgcn_mfma_f32_16x16x32_bf16(a0, bfr[ni], acc[0][ni], 0, 0, 0);
      acc[1][ni] = __builtin_amdgcn_mfma_f32_16x16x32_bf16(a1, bfr[ni], acc[1][ni], 0, 0, 0);
    }
  }

  __syncthreads();   // every wave done reading sB -> safe to overlay sC

  #pragma unroll
  for (int ni = 0; ni < 4; ++ni)
    #pragma unroll
    for (int mi = 0; mi < 2; ++mi)
      #pragma unroll
      for (int r = 0; r < 4; ++r)
        sC[(wm + mi*16 + fq*4 + r)*72 + ni*16 + fr] = acc[mi][ni][r] + bvv[ni];

  __syncthreads();   // sC visible to all waves

  const int rr = t >> 4, cl = (t & 15) * 4;
  #pragma unroll
  for (int it = 0; it < 8; ++it) {
    int row = rr + it*16;
    const float4 c  = *(const float4*)&sC[row*72 + cl];
    const float4 rv = *(const float4*)(resid + (size_t)(mbase + row)*DM + nbase + cl);
    float4 o;
    o.x = c.x + rv.x; o.y = c.y + rv.y; o.z = c.z + rv.z; o.w = c.w + rv.w;
    *(float4*)(o_f + (size_t)(mbase + row)*DM + nbase + cl) = o;
  }
}

extern "C" void kernel_launch(void* const* d_in, const int* in_sizes, int n_in,
                              void* d_out, int out_size, void* d_ws, size_t ws_size,
                              hipStream_t stream) {
  const float* x     = (const float*)d_in[0];
  const float* gamma = (const float*)d_in[1];
  const float* beta  = (const float*)d_in[2];
  const float* W_in  = (const float*)d_in[3];
  const float* b_in  = (const float*)d_in[4];
  const float* W_dt  = (const float*)d_in[5];
  const float* b_dt  = (const float*)d_in[6];
  const float* A_log = (const float*)d_in[7];
  const float* D_vec = (const float*)d_in[8];
  const float* W_out = (const float*)d_in[9];
  const float* b_out = (const float*)d_in[10];
  float* out = (float*)d_out;

  char* ws = (char*)d_ws;
  size_t off = 0;
  auto alloc = [&](size_t bytes) -> char* {
    char* p = ws + off; off += (bytes + 255) & ~(size_t)255; return p;
  };
  unsigned short* xn    = (unsigned short*)alloc((size_t)M_*DM*2);
  unsigned short* yzb   = (unsigned short*)alloc((size_t)M_*DI*2);
  unsigned short* winb  = (unsigned short*)alloc((size_t)3*DI*DM*2);
  unsigned short* woutb = (unsigned short*)alloc((size_t)DM*DI*2);
  float*          biasc = (float*)alloc((size_t)3*DI*4);
  float*          scr   = (float*)alloc((size_t)DI*4*256*4);
  float*          bscr  = (float*)alloc((size_t)DI*4*4);

  cvt_kernel<<<dim3((3*DI*DM + 255)/256), 256, 0, stream>>>(W_in, W_out, b_in, winb, woutb, biasc);
  prep1_kernel<<<dim3(DI, 4), 256, 0, stream>>>(W_in, b_in, W_dt, scr, bscr);
  prep2_kernel<<<dim3(DI), 256, 0, stream>>>(scr, bscr, b_dt, winb, biasc);
  ln_kernel<<<dim3(M_/4), 256, 0, stream>>>(x, gamma, beta, xn);
  // fused head: xp/z/dt sub-GEMMs + scan -> yz  (xp/z/dt never hit HBM)
  s6_head<<<dim3(6 * 256), 256, 0, stream>>>(xn, winb, biasc, A_log, D_vec, yzb);
  // GEMM3: yz[M,384] @ W_out[256,384]^T + b_out + residual -> out (fp32)
  gemm_out<<<dim3(256, DM/64), 256, 0, stream>>>(yzb, woutb, b_out, x, out);
}